// Round 6
// baseline (145502.466 us; speedup 1.0000x reference)
//
#include <hip/hip_runtime.h>

#define BATCH 16384
#define LOOK 30
#define HID 1024
#define DEPTH 10
#define NSTEPS 16
#define ALPHA 0.3f

typedef short bf16x8 __attribute__((ext_vector_type(8)));
typedef float f32x4 __attribute__((ext_vector_type(4)));

__device__ __forceinline__ float leaky(float x) { return x > 0.f ? x : ALPHA * x; }

__device__ __forceinline__ unsigned short f2bf(float x) {
  unsigned u = __builtin_bit_cast(unsigned, x);
  unsigned r = u + 0x7FFFu + ((u >> 16) & 1u);
  return (unsigned short)(r >> 16);
}
__device__ __forceinline__ float bf2f(unsigned short b) {
  return __builtin_bit_cast(float, (unsigned)b << 16);
}

#define GLD_LDS16(g, l)                                        \
  __builtin_amdgcn_global_load_lds(                            \
      (const __attribute__((address_space(1))) void*)(g),      \
      (__attribute__((address_space(3))) void*)(l), 16, 0, 0)

// ---------------------------------------------------------------------------
// Prep: W2[k][n] -> W2T[n][k] hi/lo bf16. grid (16,16), 256 thr.
// ---------------------------------------------------------------------------
__global__ __launch_bounds__(256) void k_w2split(const float* __restrict__ W2d,
                                                 short* __restrict__ W2Th,
                                                 short* __restrict__ W2Tl) {
  __shared__ float t[64][65];
  const int kb = blockIdx.x * 64;
  const int nb = blockIdx.y * 64;
  for (int i = threadIdx.x; i < 4096; i += 256) {
    int r = i >> 6, c = i & 63;
    t[r][c] = W2d[(size_t)(kb + r) * HID + nb + c];
  }
  __syncthreads();
  for (int i = threadIdx.x; i < 4096; i += 256) {
    int r = i >> 6, c = i & 63;
    float v = t[c][r];
    unsigned short hi = f2bf(v);
    unsigned short lo = f2bf(v - bf2f(hi));
    W2Th[(size_t)(nb + r) * HID + kb + c] = (short)hi;
    W2Tl[(size_t)(nb + r) * HID + kb + c] = (short)lo;
  }
}

// Prep: W1[30][1024] -> W1T[1024 n][32 k] hi/lo (k 30,31 zero). grid 128.
__global__ __launch_bounds__(256) void k_w1t(const float* __restrict__ W1d,
                                             short* __restrict__ W1Th,
                                             short* __restrict__ W1Tl) {
  const int idx = blockIdx.x * 256 + threadIdx.x;
  if (idx >= 1024 * 32) return;
  const int n = idx >> 5, k = idx & 31;
  float v = (k < LOOK) ? W1d[(size_t)k * HID + n] : 0.f;
  unsigned short hi = f2bf(v);
  unsigned short lo = f2bf(v - bf2f(hi));
  W1Th[idx] = (short)hi;
  W1Tl[idx] = (short)lo;
}

// Prep: W3[1024][30] -> W3T[32 n][1024 k] hi/lo (n 30,31 zero). grid 128.
__global__ __launch_bounds__(256) void k_w3t(const float* __restrict__ W3d,
                                             short* __restrict__ W3Th,
                                             short* __restrict__ W3Tl) {
  const int idx = blockIdx.x * 256 + threadIdx.x;
  if (idx >= 32 * 1024) return;
  const int n = idx >> 10, k = idx & 1023;
  float v = (n < LOOK) ? W3d[(size_t)k * LOOK + n] : 0.f;
  unsigned short hi = f2bf(v);
  unsigned short lo = f2bf(v - bf2f(hi));
  W3Th[idx] = (short)hi;
  W3Tl[idx] = (short)lo;
}

// Init: z = y0 (padded to 32 cols) hi/lo. grid 2048.
__global__ __launch_bounds__(256) void k_zinit(const float* __restrict__ y0,
                                               short* __restrict__ zh,
                                               short* __restrict__ zl) {
  const int idx = blockIdx.x * 256 + threadIdx.x;
  if (idx >= BATCH * 32) return;
  const int r = idx >> 5, c = idx & 31;
  float v = (c < LOOK) ? y0[(size_t)r * LOOK + c] : 0.f;
  unsigned short hi = f2bf(v);
  unsigned short lo = f2bf(v - bf2f(hi));
  zh[idx] = (short)hi;
  zl[idx] = (short)lo;
}

// ---------------------------------------------------------------------------
// Fused mid: H2 = leaky( leaky(z@W1+b1) @ W2 + b2 ), hi/lo out.
// 256x256 tile, BK=32 real-k, 8 waves (2M x 4N), 16x16x32 MFMA.
// A (=H1 slab) GENERATED per k-tile: h1 = z@W1-slice via swapped-operand MFMA
// (lanes hold 4 consecutive k -> ds_write_b64 into swizzled A-buf).
// B double-buffered via global_load_lds, counted vmcnt(4) (drain-0 only t=31).
// LDS: A 32KB @0 | B 2x32KB @32768. grid 256 blocks, XCD-chunked swizzle.
// ---------------------------------------------------------------------------
__global__ __launch_bounds__(512, 2) void k_mid(
    const short* __restrict__ zh, const short* __restrict__ zl,
    const short* __restrict__ W1Th, const short* __restrict__ W1Tl,
    const float* __restrict__ b1d, const short* __restrict__ W2Th,
    const short* __restrict__ W2Tl, const float* __restrict__ b2d,
    short* __restrict__ H2h, short* __restrict__ H2l) {
  __shared__ char lds[98304];

  const int tid = threadIdx.x;
  const int lane = tid & 63;
  const int wave = tid >> 6;

  const int bid = blockIdx.x;
  const int wg = (bid & 7) * 32 + (bid >> 3);
  const int mb = wg >> 2, nb = wg & 3;
  const int row0 = mb * 256;
  const int n0 = nb * 256;
  const int wm = wave >> 2;   // 0..1 (128-row half)
  const int wnb = wave & 3;   // 0..3 (64-col quarter)
  const int r15 = lane & 15;
  const int kq = lane >> 4;   // 0..3
  const int l7 = lane & 7;
  const int l3 = lane >> 3;   // 0..7

  // ---- B staging: 4 chunks of 1KB per wave, pre-swizzled global source
  const char* srcB[4];
  {
    const int s = l7 ^ l3;  // logical slot fetched into phys slot l7
    const char* base = (s < 4) ? (const char*)W2Th : (const char*)W2Tl;
#pragma unroll
    for (int i = 0; i < 4; ++i) {
      const int c = wave * 4 + i;
      srcB[i] = base + (size_t)(n0 + c * 8 + l3) * 2048 + (size_t)(s & 3) * 16;
    }
  }

  // ---- z fragments (persistent): rows = row0 + wave*32 + rt*16 + r15
  bf16x8 zf[2][2];
#pragma unroll
  for (int rt = 0; rt < 2; ++rt) {
    const size_t zo = (size_t)(row0 + wave * 32 + rt * 16 + r15) * 32 + kq * 8;
    zf[rt][0] = *(const bf16x8*)&zh[zo];
    zf[rt][1] = *(const bf16x8*)&zl[zo];
  }

  // ---- mid fragment read offsets (phys slot = log ^ (row&7), row&7 == l7)
  const int offA0 = (wm * 128 + r15) * 128 + ((0 + kq) ^ l7) * 16;
  const int offA1 = (wm * 128 + r15) * 128 + ((4 + kq) ^ l7) * 16;
  const int offB0 = (wnb * 64 + r15) * 128 + ((0 + kq) ^ l7) * 16;
  const int offB1 = (wnb * 64 + r15) * 128 + ((4 + kq) ^ l7) * 16;

  f32x4 acc[8][4];
#pragma unroll
  for (int i = 0; i < 8; ++i)
#pragma unroll
    for (int j = 0; j < 4; ++j) acc[i][j] = (f32x4){0.f, 0.f, 0.f, 0.f};

  // prologue: stage B(0) into buf 0
#pragma unroll
  for (int i = 0; i < 4; ++i)
    GLD_LDS16(srcB[i], &lds[32768 + (wave * 4 + i) * 1024]);

  for (int t = 0; t < 32; ++t) {
    // W1 frags + b1 for tile t (L2-broadcast; consumed before barrier1)
    bf16x8 w1[2][2];
    float4 b1v[2];
#pragma unroll
    for (int kt = 0; kt < 2; ++kt) {
      const size_t wo = (size_t)(t * 32 + kt * 16 + r15) * 32 + kq * 8;
      w1[kt][0] = *(const bf16x8*)&W1Th[wo];
      w1[kt][1] = *(const bf16x8*)&W1Tl[wo];
      b1v[kt] = *(const float4*)&b1d[t * 32 + kt * 16 + kq * 4];
    }

    // stage B(t+1) (newest 4 VMEM ops at barrier1)
    if (t < 31) {
      const int kb = (t + 1) * 64;
      char* dst = &lds[32768 + ((t + 1) & 1) * 32768];
#pragma unroll
      for (int i = 0; i < 4; ++i)
        GLD_LDS16(srcB[i] + kb, dst + (wave * 4 + i) * 1024);
    }

    // H1-gen: D[k-row][h1row-col] = sum_zk W1piece * zpiece (12 MFMA)
    f32x4 h1a[2][2];
#pragma unroll
    for (int kt = 0; kt < 2; ++kt)
#pragma unroll
      for (int rt = 0; rt < 2; ++rt) {
        f32x4 a = (f32x4){0.f, 0.f, 0.f, 0.f};
        a = __builtin_amdgcn_mfma_f32_16x16x32_bf16(w1[kt][0], zf[rt][0], a, 0, 0, 0);
        a = __builtin_amdgcn_mfma_f32_16x16x32_bf16(w1[kt][1], zf[rt][0], a, 0, 0, 0);
        a = __builtin_amdgcn_mfma_f32_16x16x32_bf16(w1[kt][0], zf[rt][1], a, 0, 0, 0);
        h1a[kt][rt] = a;
      }

    // bias + leaky + hi/lo split + b64 write into swizzled A-buf
#pragma unroll
    for (int kt = 0; kt < 2; ++kt)
#pragma unroll
      for (int rt = 0; rt < 2; ++rt) {
        unsigned short hs[4], ls[4];
#pragma unroll
        for (int r = 0; r < 4; ++r) {
          float v = leaky(h1a[kt][rt][r] + b1v[kt][r]);
          hs[r] = f2bf(v);
          ls[r] = f2bf(v - bf2f(hs[r]));
        }
        const int row = wave * 32 + rt * 16 + r15;
        const int bb = row * 128 + (kq & 1) * 8;
        const int so = kt * 2 + (kq >> 1);  // k-oct 0..3
        const int sh = ((0 + so) ^ l7) * 16;
        const int sl = ((4 + so) ^ l7) * 16;
        uint2 hp, lp;
        hp.x = (unsigned)hs[0] | ((unsigned)hs[1] << 16);
        hp.y = (unsigned)hs[2] | ((unsigned)hs[3] << 16);
        lp.x = (unsigned)ls[0] | ((unsigned)ls[1] << 16);
        lp.y = (unsigned)ls[2] | ((unsigned)ls[3] << 16);
        *(uint2*)&lds[bb + sh] = hp;
        *(uint2*)&lds[bb + sl] = lp;
      }

    // barrier 1: A written, B(t) landed; B(t+1) stays in flight (counted)
    __builtin_amdgcn_sched_barrier(0);
    if (t < 31) {
      asm volatile("s_waitcnt vmcnt(4) lgkmcnt(0)" ::: "memory");
    } else {
      asm volatile("s_waitcnt vmcnt(0) lgkmcnt(0)" ::: "memory");
    }
    __builtin_amdgcn_sched_barrier(0);
    __builtin_amdgcn_s_barrier();

    // mid MFMA: 96 per wave
    const char* bufB = &lds[32768 + (t & 1) * 32768];
    bf16x8 bh[4], bl[4];
#pragma unroll
    for (int nj = 0; nj < 4; ++nj) {
      bh[nj] = *(const bf16x8*)(bufB + offB0 + nj * 2048);
      bl[nj] = *(const bf16x8*)(bufB + offB1 + nj * 2048);
    }
    __builtin_amdgcn_s_setprio(1);
#pragma unroll
    for (int mi = 0; mi < 8; ++mi) {
      bf16x8 ah = *(const bf16x8*)(lds + offA0 + mi * 2048);
      bf16x8 al = *(const bf16x8*)(lds + offA1 + mi * 2048);
#pragma unroll
      for (int nj = 0; nj < 4; ++nj) {
        acc[mi][nj] =
            __builtin_amdgcn_mfma_f32_16x16x32_bf16(ah, bh[nj], acc[mi][nj], 0, 0, 0);
        acc[mi][nj] =
            __builtin_amdgcn_mfma_f32_16x16x32_bf16(ah, bl[nj], acc[mi][nj], 0, 0, 0);
        acc[mi][nj] =
            __builtin_amdgcn_mfma_f32_16x16x32_bf16(al, bh[nj], acc[mi][nj], 0, 0, 0);
      }
    }
    __builtin_amdgcn_s_setprio(0);

    // barrier 2: protects A-buf rewrite and B-buf reuse next tile
    __builtin_amdgcn_sched_barrier(0);
    __builtin_amdgcn_s_barrier();
  }

  // epilogue: C/D col = lane&15 (N), row = (lane>>4)*4 + reg (M)
  const int crow = (lane >> 4) * 4;
#pragma unroll
  for (int nj = 0; nj < 4; ++nj) {
    const int col = n0 + wnb * 64 + nj * 16 + r15;
    const float bv = b2d[col];
#pragma unroll
    for (int mi = 0; mi < 8; ++mi) {
      const int rb = row0 + wm * 128 + mi * 16 + crow;
#pragma unroll
      for (int r = 0; r < 4; ++r) {
        float v = leaky(acc[mi][nj][r] + bv);
        unsigned short hi = f2bf(v);
        unsigned short lo = f2bf(v - bf2f(hi));
        const size_t o = (size_t)(rb + r) * HID + col;
        H2h[o] = (short)hi;
        H2l[o] = (short)lo;
      }
    }
  }
}

// ---------------------------------------------------------------------------
// Layer3 (MFMA): kout = H2 @ W3 + b3; fused DoPri combine and/or next-z.
// Block 256 thr / 4 waves (2M x 2N), tile M=32 x N=32, K=1024 in 32 tiles.
// grid BATCH/32 = 512.
// ---------------------------------------------------------------------------
__global__ __launch_bounds__(256, 4) void k_l3(
    const short* __restrict__ H2h, const short* __restrict__ H2l,
    const short* __restrict__ W3Th, const short* __restrict__ W3Tl,
    const float* __restrict__ b3d, float* __restrict__ kout,
    const float* __restrict__ K0, const float* __restrict__ K1,
    const float* __restrict__ K2, const float* __restrict__ K3,
    const float* __restrict__ K4, float* __restrict__ y,
    short* __restrict__ zh, short* __restrict__ zl, int combine, float p1,
    float p2, float p3, float p4, float p5, float pc, float hb1, float hb2,
    float hb3, float hb4, float hb5, float hb6) {
  __shared__ short lds[2][4096];

  const int tid = threadIdx.x, lane = tid & 63, wave = tid >> 6;
  const int row0 = blockIdx.x * 32;
  const int wm = wave & 1, wn = wave >> 1;

  const int half = tid >> 7;
  const int idx = tid & 127;
  const int srow = idx >> 2;
  const int sd = idx & 3;
  const int slog = sd ^ ((srow >> 1) & 3);
  const short* Asrc = half ? H2l : H2h;
  const short* Bsrc = half ? W3Tl : W3Th;
  const char* aSrc = (const char*)(Asrc + (size_t)(row0 + srow) * HID) + slog * 16;
  const char* bSrc = (const char*)(Bsrc + (size_t)srow * HID) + slog * 16;
  short* aDst0 = &lds[0][half * 1024 + idx * 8];
  short* bDst0 = &lds[0][2048 + half * 1024 + idx * 8];
  short* aDst1 = &lds[1][half * 1024 + idx * 8];
  short* bDst1 = &lds[1][2048 + half * 1024 + idx * 8];

  const int r15 = lane & 15;
  const int kc = lane >> 4;
  const int aRow = wm * 16 + r15;
  const int bRow = wn * 16 + r15;
  const int aOff = aRow * 32 + (kc ^ ((aRow >> 1) & 3)) * 8;
  const int bOff = 2048 + bRow * 32 + (kc ^ ((bRow >> 1) & 3)) * 8;

  f32x4 acc = (f32x4){0.f, 0.f, 0.f, 0.f};

#define STAGE3(ad, bd, kb)          \
  {                                 \
    GLD_LDS16(aSrc + (kb), (ad));   \
    GLD_LDS16(bSrc + (kb), (bd));   \
  }

  STAGE3(aDst0, bDst0, 0);
  __syncthreads();

  for (int t = 0; t < 32; ++t) {
    const int cur = t & 1;
    if (t < 31) {
      if (cur == 0) STAGE3(aDst1, bDst1, (t + 1) * 64)
      else STAGE3(aDst0, bDst0, (t + 1) * 64)
    }
    const short* buf = lds[cur];
    bf16x8 ah = *(const bf16x8*)(buf + aOff);
    bf16x8 al = *(const bf16x8*)(buf + 1024 + aOff);
    bf16x8 bh = *(const bf16x8*)(buf + bOff);
    bf16x8 bl = *(const bf16x8*)(buf + 1024 + bOff);
    acc = __builtin_amdgcn_mfma_f32_16x16x32_bf16(ah, bh, acc, 0, 0, 0);
    acc = __builtin_amdgcn_mfma_f32_16x16x32_bf16(ah, bl, acc, 0, 0, 0);
    acc = __builtin_amdgcn_mfma_f32_16x16x32_bf16(al, bh, acc, 0, 0, 0);
    __syncthreads();
  }
#undef STAGE3

  const int c = wn * 16 + r15;
  const int rb = row0 + wm * 16 + (lane >> 4) * 4;
  const float bias = (c < LOOK) ? b3d[c] : 0.f;
#pragma unroll
  for (int r = 0; r < 4; ++r) {
    const int row = rb + r;
    const float kv = acc[r] + bias;
    float zv = 0.f;
    if (c < LOOK) {
      const size_t id = (size_t)row * LOOK + c;
      const float yv = y[id];
      if (combine) {
        float yn = yv + hb1 * K0[id] + hb2 * K1[id] + hb3 * K2[id] +
                   hb4 * K3[id] + hb5 * K4[id] + hb6 * kv;
        y[id] = yn;
        zv = yn;
      } else {
        kout[id] = kv;
        zv = yv + pc * kv;
        if (p1 != 0.f) zv += p1 * K0[id];
        if (p2 != 0.f) zv += p2 * K1[id];
        if (p3 != 0.f) zv += p3 * K2[id];
        if (p4 != 0.f) zv += p4 * K3[id];
        if (p5 != 0.f) zv += p5 * K4[id];
      }
    }
    unsigned short hi = f2bf(zv);
    unsigned short lo = f2bf(zv - bf2f(hi));
    const size_t zo = (size_t)row * 32 + c;
    zh[zo] = (short)hi;
    zl[zo] = (short)lo;
  }
}

// ---------------------------------------------------------------------------
__global__ __launch_bounds__(256) void k_readout(const float* __restrict__ y,
                                                 const float* __restrict__ Wf,
                                                 const float* __restrict__ bf,
                                                 float* __restrict__ out) {
  const int r = blockIdx.x * blockDim.x + threadIdx.x;
  if (r >= BATCH) return;
  float acc = bf[0];
#pragma unroll
  for (int c = 0; c < LOOK; ++c) acc += y[(size_t)r * LOOK + c] * Wf[c];
  out[r] = acc;
}

// ---------------------------------------------------------------------------
extern "C" void kernel_launch(void* const* d_in, const int* in_sizes, int n_in,
                              void* d_out, int out_size, void* d_ws,
                              size_t ws_size, hipStream_t stream) {
  const float* y0 = (const float*)d_in[0];
  const float* W1 = (const float*)d_in[1];
  const float* b1 = (const float*)d_in[2];
  const float* W2 = (const float*)d_in[3];
  const float* b2 = (const float*)d_in[4];
  const float* W3 = (const float*)d_in[5];
  const float* b3 = (const float*)d_in[6];
  const float* Wf = (const float*)d_in[7];
  const float* bf = (const float*)d_in[8];
  float* out = (float*)d_out;

  const size_t NY = (size_t)BATCH * LOOK;
  float* f = (float*)d_ws;
  float* y = f;
  float* kk[5];
  for (int i = 0; i < 5; ++i) kk[i] = f + NY * (1 + i);
  char* p = (char*)(f + NY * 6);
  short* zh = (short*)p; p += (size_t)BATCH * 32 * 2;
  short* zl = (short*)p; p += (size_t)BATCH * 32 * 2;
  short* H2h = (short*)p; p += (size_t)BATCH * HID * 2;
  short* H2l = (short*)p; p += (size_t)BATCH * HID * 2;
  short* W2Th = (short*)p; p += (size_t)HID * HID * 2;
  short* W2Tl = (short*)p; p += (size_t)HID * HID * 2;
  short* W1Th = (short*)p; p += (size_t)HID * 32 * 2;
  short* W1Tl = (short*)p; p += (size_t)HID * 32 * 2;
  short* W3Th = (short*)p; p += (size_t)32 * HID * 2;
  short* W3Tl = (short*)p;

  hipMemcpyAsync(y, y0, NY * sizeof(float), hipMemcpyDeviceToDevice, stream);
  k_zinit<<<dim3(BATCH * 32 / 256), 256, 0, stream>>>(y0, zh, zl);

  const double hh = 1.0 / 16.0;
  static const double A[6][5] = {
      {0, 0, 0, 0, 0},
      {1.0 / 5, 0, 0, 0, 0},
      {3.0 / 40, 9.0 / 40, 0, 0, 0},
      {44.0 / 45, -56.0 / 15, 32.0 / 9, 0, 0},
      {19372.0 / 6561, -25360.0 / 2187, 64448.0 / 6561, -212.0 / 729, 0},
      {9017.0 / 3168, -355.0 / 33, 46732.0 / 5247, 49.0 / 176,
       -5103.0 / 18656},
  };
  static const double Bb[6] = {35.0 / 384,  0,              500.0 / 1113,
                               125.0 / 192, -2187.0 / 6784, 11.0 / 84};

  const float hb1 = (float)(hh * Bb[0]);
  const float hb2 = (float)(hh * Bb[1]);
  const float hb3 = (float)(hh * Bb[2]);
  const float hb4 = (float)(hh * Bb[3]);
  const float hb5 = (float)(hh * Bb[4]);
  const float hb6 = (float)(hh * Bb[5]);

  for (int d = 0; d < DEPTH; ++d) {
    const float* W1d = W1 + (size_t)d * LOOK * HID;
    const float* b1d = b1 + (size_t)d * HID;
    const float* W2d = W2 + (size_t)d * HID * HID;
    const float* b2d = b2 + (size_t)d * HID;
    const float* W3d = W3 + (size_t)d * HID * LOOK;
    const float* b3d = b3 + (size_t)d * LOOK;

    k_w2split<<<dim3(16, 16), 256, 0, stream>>>(W2d, W2Th, W2Tl);
    k_w1t<<<dim3(128), 256, 0, stream>>>(W1d, W1Th, W1Tl);
    k_w3t<<<dim3(128), 256, 0, stream>>>(W3d, W3Th, W3Tl);

    for (int s = 0; s < NSTEPS; ++s) {
      for (int st = 0; st < 6; ++st) {
        float pv[5] = {0.f, 0.f, 0.f, 0.f, 0.f};
        float pc = 0.f;
        if (st < 5) {
          for (int jj = 0; jj < 5; ++jj)
            if (jj < st) pv[jj] = (float)(hh * A[st + 1][jj]);
          pc = (float)(hh * A[st + 1][st]);
        }
        k_mid<<<dim3(256), 512, 0, stream>>>(zh, zl, W1Th, W1Tl, b1d, W2Th,
                                             W2Tl, b2d, H2h, H2l);
        const int comb = (st == 5) ? 1 : 0;
        float* kout = (st < 5) ? kk[st] : kk[0];
        k_l3<<<dim3(BATCH / 32), 256, 0, stream>>>(
            H2h, H2l, W3Th, W3Tl, b3d, kout, kk[0], kk[1], kk[2], kk[3],
            kk[4], y, zh, zl, comb, pv[0], pv[1], pv[2], pv[3], pv[4], pc,
            hb1, hb2, hb3, hb4, hb5, hb6);
      }
    }
  }

  k_readout<<<dim3(BATCH / 256), 256, 0, stream>>>(y, Wf, bf, out);
}

// Round 7
// 140815.247 us; speedup vs baseline: 1.0333x; 1.0333x over previous
//
#include <hip/hip_runtime.h>

#define BATCH 16384
#define LOOK 30
#define HID 1024
#define DEPTH 10
#define NSTEPS 16
#define ALPHA 0.3f

typedef short bf16x8 __attribute__((ext_vector_type(8)));
typedef float f32x4 __attribute__((ext_vector_type(4)));

__device__ __forceinline__ float leaky(float x) { return x > 0.f ? x : ALPHA * x; }

__device__ __forceinline__ unsigned short f2bf(float x) {
  unsigned u = __builtin_bit_cast(unsigned, x);
  unsigned r = u + 0x7FFFu + ((u >> 16) & 1u);
  return (unsigned short)(r >> 16);
}
__device__ __forceinline__ float bf2f(unsigned short b) {
  return __builtin_bit_cast(float, (unsigned)b << 16);
}

#define GLD_LDS16(g, l)                                        \
  __builtin_amdgcn_global_load_lds(                            \
      (const __attribute__((address_space(1))) void*)(g),      \
      (__attribute__((address_space(3))) void*)(l), 16, 0, 0)

#define SBAR()                               \
  {                                          \
    __builtin_amdgcn_sched_barrier(0);       \
    __builtin_amdgcn_s_barrier();            \
  }
#define WAIT_LGKM0()                                          \
  {                                                           \
    __builtin_amdgcn_sched_barrier(0);                        \
    asm volatile("s_waitcnt lgkmcnt(0)" ::: "memory");        \
    __builtin_amdgcn_sched_barrier(0);                        \
  }
#define WAIT_VM(n)                                            \
  {                                                           \
    __builtin_amdgcn_sched_barrier(0);                        \
    asm volatile("s_waitcnt vmcnt(" #n ")" ::: "memory");     \
    __builtin_amdgcn_sched_barrier(0);                        \
  }

// ---------------------------------------------------------------------------
// Prep: W2[k][n] -> W2T[n][k] hi/lo bf16. grid (16,16), 256 thr.
// ---------------------------------------------------------------------------
__global__ __launch_bounds__(256) void k_w2split(const float* __restrict__ W2d,
                                                 short* __restrict__ W2Th,
                                                 short* __restrict__ W2Tl) {
  __shared__ float t[64][65];
  const int kb = blockIdx.x * 64;
  const int nb = blockIdx.y * 64;
  for (int i = threadIdx.x; i < 4096; i += 256) {
    int r = i >> 6, c = i & 63;
    t[r][c] = W2d[(size_t)(kb + r) * HID + nb + c];
  }
  __syncthreads();
  for (int i = threadIdx.x; i < 4096; i += 256) {
    int r = i >> 6, c = i & 63;
    float v = t[c][r];
    unsigned short hi = f2bf(v);
    unsigned short lo = f2bf(v - bf2f(hi));
    W2Th[(size_t)(nb + r) * HID + kb + c] = (short)hi;
    W2Tl[(size_t)(nb + r) * HID + kb + c] = (short)lo;
  }
}

// Prep: W1[30][1024] -> W1T[1024 n][32 k] hi/lo (k 30,31 zero). grid 128.
__global__ __launch_bounds__(256) void k_w1t(const float* __restrict__ W1d,
                                             short* __restrict__ W1Th,
                                             short* __restrict__ W1Tl) {
  const int idx = blockIdx.x * 256 + threadIdx.x;
  if (idx >= 1024 * 32) return;
  const int n = idx >> 5, k = idx & 31;
  float v = (k < LOOK) ? W1d[(size_t)k * HID + n] : 0.f;
  unsigned short hi = f2bf(v);
  unsigned short lo = f2bf(v - bf2f(hi));
  W1Th[idx] = (short)hi;
  W1Tl[idx] = (short)lo;
}

// Prep: W3[1024][30] -> W3T[32 n][1024 k] hi/lo (n 30,31 zero). grid 128.
__global__ __launch_bounds__(256) void k_w3t(const float* __restrict__ W3d,
                                             short* __restrict__ W3Th,
                                             short* __restrict__ W3Tl) {
  const int idx = blockIdx.x * 256 + threadIdx.x;
  if (idx >= 32 * 1024) return;
  const int n = idx >> 10, k = idx & 1023;
  float v = (n < LOOK) ? W3d[(size_t)k * LOOK + n] : 0.f;
  unsigned short hi = f2bf(v);
  unsigned short lo = f2bf(v - bf2f(hi));
  W3Th[idx] = (short)hi;
  W3Tl[idx] = (short)lo;
}

// Init: z = y0 (padded to 32 cols) hi/lo. grid 2048.
__global__ __launch_bounds__(256) void k_zinit(const float* __restrict__ y0,
                                               short* __restrict__ zh,
                                               short* __restrict__ zl) {
  const int idx = blockIdx.x * 256 + threadIdx.x;
  if (idx >= BATCH * 32) return;
  const int r = idx >> 5, c = idx & 31;
  float v = (c < LOOK) ? y0[(size_t)r * LOOK + c] : 0.f;
  unsigned short hi = f2bf(v);
  unsigned short lo = f2bf(v - bf2f(hi));
  zh[idx] = (short)hi;
  zl[idx] = (short)lo;
}

// ---------------------------------------------------------------------------
// Layer1 (MFMA): H1 = leaky(z @ W1 + b1), single K-tile (K=32).
// Block 512 thr / 8 waves (2M x 4N), tile M=128 x N=256, wave 64x64.
// grid (BATCH/128, HID/256) = (128, 4).   [R4 verbatim]
// ---------------------------------------------------------------------------
__global__ __launch_bounds__(512, 2) void k_l1(
    const short* __restrict__ zh, const short* __restrict__ zl,
    const short* __restrict__ W1Th, const short* __restrict__ W1Tl,
    const float* __restrict__ b1d, short* __restrict__ H1h,
    short* __restrict__ H1l) {
  __shared__ short za[2][128 * 32];
  const int tid = threadIdx.x, lane = tid & 63, wave = tid >> 6;
  const int row0 = blockIdx.x * 128;
  const int n0 = blockIdx.y * 256;
  const int wm = wave >> 2, wn = wave & 3;
  const int r15 = lane & 15;
  const int bk = (lane >> 4) * 8;

  bf16x8 bh[4], bl[4];
#pragma unroll
  for (int nj = 0; nj < 4; ++nj) {
    const size_t bo = (size_t)(n0 + wn * 64 + nj * 16 + r15) * 32 + bk;
    bh[nj] = *(const bf16x8*)&W1Th[bo];
    bl[nj] = *(const bf16x8*)&W1Tl[bo];
  }

  GLD_LDS16((const char*)(zh + (size_t)row0 * 32) + tid * 16, &za[0][tid * 8]);
  GLD_LDS16((const char*)(zl + (size_t)row0 * 32) + tid * 16, &za[1][tid * 8]);
  __syncthreads();

  bf16x8 ah[4], al[4];
#pragma unroll
  for (int mi = 0; mi < 4; ++mi) {
    const int ao = (wm * 64 + mi * 16 + r15) * 32 + bk;
    ah[mi] = *(const bf16x8*)&za[0][ao];
    al[mi] = *(const bf16x8*)&za[1][ao];
  }

  f32x4 acc[4][4];
#pragma unroll
  for (int i = 0; i < 4; ++i)
#pragma unroll
    for (int j = 0; j < 4; ++j) acc[i][j] = (f32x4){0.f, 0.f, 0.f, 0.f};

#pragma unroll
  for (int mi = 0; mi < 4; ++mi)
#pragma unroll
    for (int nj = 0; nj < 4; ++nj) {
      acc[mi][nj] = __builtin_amdgcn_mfma_f32_16x16x32_bf16(ah[mi], bh[nj],
                                                            acc[mi][nj], 0, 0, 0);
      acc[mi][nj] = __builtin_amdgcn_mfma_f32_16x16x32_bf16(ah[mi], bl[nj],
                                                            acc[mi][nj], 0, 0, 0);
      acc[mi][nj] = __builtin_amdgcn_mfma_f32_16x16x32_bf16(al[mi], bh[nj],
                                                            acc[mi][nj], 0, 0, 0);
    }

  const int crow = (lane >> 4) * 4;
#pragma unroll
  for (int nj = 0; nj < 4; ++nj) {
    const int col = n0 + wn * 64 + nj * 16 + r15;
    const float bias = b1d[col];
#pragma unroll
    for (int mi = 0; mi < 4; ++mi) {
      const int rb = row0 + wm * 64 + mi * 16 + crow;
#pragma unroll
      for (int r = 0; r < 4; ++r) {
        float v = leaky(acc[mi][nj][r] + bias);
        unsigned short hi = f2bf(v);
        unsigned short lo = f2bf(v - bf2f(hi));
        const size_t o = (size_t)(rb + r) * HID + col;
        H1h[o] = (short)hi;
        H1l[o] = (short)lo;
      }
    }
  }
}

// ---------------------------------------------------------------------------
// Mid (MFMA): H2 = leaky(H1 @ W2 + b2), split-bf16 3-product.
// 256x256 tile, BK=32 real-k, 8 waves (2M x 4N), 16x16x32.
// Phase-split schedule per K-tile:
//   Phase A: ds_read B(8)+A half0(8); issue ALL 8 next-tile gld_lds;
//            barrier; lgkmcnt(0); setprio1; 48 MFMA; setprio0; barrier.
//   Phase B: ds_read A half1(8); barrier; lgkmcnt(0); 48 MFMA;
//            vmcnt(0) (issued ~1.5 phases ago -> cheap); barrier.
// LDS: BUF0 {A@0,B@32768}, BUF1 {A@65536,B@98304} = 128KB.
// grid 256 blocks (64M x 4N), XCD-chunked swizzle.
// ---------------------------------------------------------------------------
__global__ __launch_bounds__(512, 2) void k_mid(
    const short* __restrict__ H1h, const short* __restrict__ H1l,
    const short* __restrict__ W2Th, const short* __restrict__ W2Tl,
    const float* __restrict__ b2d, short* __restrict__ H2h,
    short* __restrict__ H2l) {
  __shared__ char lds[131072];

  const int tid = threadIdx.x;
  const int lane = tid & 63;
  const int wave = tid >> 6;

  const int bid = blockIdx.x;
  const int wg = (bid & 7) * 32 + (bid >> 3);
  const int mb = wg >> 2, nb = wg & 3;
  const int row0 = mb * 256;
  const int n0 = nb * 256;
  const int wm = wave >> 2;
  const int wnb = wave & 3;
  const int r15 = lane & 15;
  const int kq = lane >> 4;
  const int l7 = lane & 7;
  const int l3 = lane >> 3;

  // ---- staging sources (pre-swizzled; wave 0-3 -> A, 4-7 -> B)
  const char* srcB[8];
  {
    const int s = l7 ^ l3;
    const char* hsrc;
    const char* lsrc;
    int rbase;
    if (wave < 4) {
      hsrc = (const char*)H1h;
      lsrc = (const char*)H1l;
      rbase = row0;
    } else {
      hsrc = (const char*)W2Th;
      lsrc = (const char*)W2Tl;
      rbase = n0;
    }
    const char* base = (s < 4) ? hsrc : lsrc;
#pragma unroll
    for (int i = 0; i < 8; ++i) {
      const int c = wave * 8 + i;
      const int rloc = (c & 31) * 8 + l3;
      srcB[i] = base + (size_t)(rbase + rloc) * 2048 + (size_t)(s & 3) * 16;
    }
  }
  const int dchunk0 = wave * 8192;

  // ---- fragment read offsets (phys slot = log ^ (row&7); row&7 == l7)
  const int offA0 = (wm * 128 + r15) * 128 + ((0 + kq) ^ l7) * 16;
  const int offA1 = (wm * 128 + r15) * 128 + ((4 + kq) ^ l7) * 16;
  const int offB0 = 32768 + (wnb * 64 + r15) * 128 + ((0 + kq) ^ l7) * 16;
  const int offB1 = 32768 + (wnb * 64 + r15) * 128 + ((4 + kq) ^ l7) * 16;

  f32x4 acc[8][4];
#pragma unroll
  for (int i = 0; i < 8; ++i)
#pragma unroll
    for (int j = 0; j < 4; ++j) acc[i][j] = (f32x4){0.f, 0.f, 0.f, 0.f};

#define STAGE4(bufbase, kb, h)                                             \
  {                                                                        \
    _Pragma("unroll") for (int i_ = 0; i_ < 4; ++i_) {                     \
      GLD_LDS16(srcB[(h)*4 + i_] + (kb),                                   \
                &lds[(bufbase) + dchunk0 + ((h)*4 + i_) * 1024]);          \
    }                                                                      \
  }

  // prologue: tile 0 -> BUF0
  STAGE4(0, 0, 0);
  STAGE4(0, 0, 1);
  WAIT_VM(0);
  SBAR();

  for (int tt = 0; tt < 32; ++tt) {
    const int rb = (tt & 1) * 65536;        // buffer holding tile tt
    const int wb = ((tt + 1) & 1) * 65536;  // buffer for tile tt+1
    const int kb = (tt + 1) * 64;

    bf16x8 bh[4], bl[4], ah[4], al[4];

    // ---------------- Phase A: B-all + A-half0 reads, full next-tile stage
#pragma unroll
    for (int nj = 0; nj < 4; ++nj) {
      bh[nj] = *(const bf16x8*)(lds + rb + offB0 + nj * 2048);
      bl[nj] = *(const bf16x8*)(lds + rb + offB1 + nj * 2048);
    }
#pragma unroll
    for (int q = 0; q < 4; ++q) {
      ah[q] = *(const bf16x8*)(lds + rb + offA0 + q * 2048);
      al[q] = *(const bf16x8*)(lds + rb + offA1 + q * 2048);
    }
    if (tt < 31) {
      STAGE4(wb, kb, 0);
      STAGE4(wb, kb, 1);
    }
    SBAR();
    WAIT_LGKM0();
    __builtin_amdgcn_s_setprio(1);
#pragma unroll
    for (int q = 0; q < 4; ++q)
#pragma unroll
      for (int nj = 0; nj < 4; ++nj) {
        acc[q][nj] =
            __builtin_amdgcn_mfma_f32_16x16x32_bf16(ah[q], bh[nj], acc[q][nj], 0, 0, 0);
        acc[q][nj] =
            __builtin_amdgcn_mfma_f32_16x16x32_bf16(ah[q], bl[nj], acc[q][nj], 0, 0, 0);
        acc[q][nj] =
            __builtin_amdgcn_mfma_f32_16x16x32_bf16(al[q], bh[nj], acc[q][nj], 0, 0, 0);
      }
    __builtin_amdgcn_s_setprio(0);
    SBAR();

    // ---------------- Phase B: A-half1 reads
#pragma unroll
    for (int q = 0; q < 4; ++q) {
      ah[q] = *(const bf16x8*)(lds + rb + offA0 + (4 + q) * 2048);
      al[q] = *(const bf16x8*)(lds + rb + offA1 + (4 + q) * 2048);
    }
    SBAR();
    WAIT_LGKM0();
    __builtin_amdgcn_s_setprio(1);
#pragma unroll
    for (int q = 0; q < 4; ++q)
#pragma unroll
      for (int nj = 0; nj < 4; ++nj) {
        acc[4 + q][nj] =
            __builtin_amdgcn_mfma_f32_16x16x32_bf16(ah[q], bh[nj], acc[4 + q][nj], 0, 0, 0);
        acc[4 + q][nj] =
            __builtin_amdgcn_mfma_f32_16x16x32_bf16(ah[q], bl[nj], acc[4 + q][nj], 0, 0, 0);
        acc[4 + q][nj] =
            __builtin_amdgcn_mfma_f32_16x16x32_bf16(al[q], bh[nj], acc[4 + q][nj], 0, 0, 0);
      }
    __builtin_amdgcn_s_setprio(0);
    // gate: next tile's buffer must be fully landed before anyone reads it
    WAIT_VM(0);
    SBAR();
  }
#undef STAGE4

  // epilogue: C/D col = lane&15 (N), row = (lane>>4)*4 + reg (M)
  const int crow = (lane >> 4) * 4;
#pragma unroll
  for (int nj = 0; nj < 4; ++nj) {
    const int col = n0 + wnb * 64 + nj * 16 + r15;
    const float bv = b2d[col];
#pragma unroll
    for (int mi = 0; mi < 8; ++mi) {
      const int rbrow = row0 + wm * 128 + mi * 16 + crow;
#pragma unroll
      for (int r = 0; r < 4; ++r) {
        float v = leaky(acc[mi][nj][r] + bv);
        unsigned short hi = f2bf(v);
        unsigned short lo = f2bf(v - bf2f(hi));
        const size_t o = (size_t)(rbrow + r) * HID + col;
        H2h[o] = (short)hi;
        H2l[o] = (short)lo;
      }
    }
  }
}

// ---------------------------------------------------------------------------
// Layer3 (MFMA): kout = H2 @ W3 + b3; fused DoPri combine / next-z.
// 4-slot LDS ring, prefetch distance 2, counted vmcnt(2) (never drains).
// Block 256 thr / 4 waves, tile M=32 x N=32, K=1024 in 32 tiles. grid 512.
// ---------------------------------------------------------------------------
__global__ __launch_bounds__(256, 4) void k_l3(
    const short* __restrict__ H2h, const short* __restrict__ H2l,
    const short* __restrict__ W3Th, const short* __restrict__ W3Tl,
    const float* __restrict__ b3d, float* __restrict__ kout,
    const float* __restrict__ K0, const float* __restrict__ K1,
    const float* __restrict__ K2, const float* __restrict__ K3,
    const float* __restrict__ K4, float* __restrict__ y,
    short* __restrict__ zh, short* __restrict__ zl, int combine, float p1,
    float p2, float p3, float p4, float p5, float pc, float hb1, float hb2,
    float hb3, float hb4, float hb5, float hb6) {
  __shared__ short lds[4][4096];

  const int tid = threadIdx.x, lane = tid & 63, wave = tid >> 6;
  const int row0 = blockIdx.x * 32;
  const int wm = wave & 1, wn = wave >> 1;

  const int half = tid >> 7;
  const int idx = tid & 127;
  const int srow = idx >> 2;
  const int sd = idx & 3;
  const int slog = sd ^ ((srow >> 1) & 3);
  const short* Asrc = half ? H2l : H2h;
  const short* Bsrc = half ? W3Tl : W3Th;
  const char* aSrc = (const char*)(Asrc + (size_t)(row0 + srow) * HID) + slog * 16;
  const char* bSrc = (const char*)(Bsrc + (size_t)srow * HID) + slog * 16;
  short* aDst[4];
  short* bDst[4];
#pragma unroll
  for (int s = 0; s < 4; ++s) {
    aDst[s] = &lds[s][half * 1024 + idx * 8];
    bDst[s] = &lds[s][2048 + half * 1024 + idx * 8];
  }

  const int r15 = lane & 15;
  const int kc = lane >> 4;
  const int aRow = wm * 16 + r15;
  const int bRow = wn * 16 + r15;
  const int aOff = aRow * 32 + (kc ^ ((aRow >> 1) & 3)) * 8;
  const int bOff = 2048 + bRow * 32 + (kc ^ ((bRow >> 1) & 3)) * 8;

  f32x4 acc = (f32x4){0.f, 0.f, 0.f, 0.f};

#define STG(s, kb)                        \
  {                                       \
    GLD_LDS16(aSrc + (kb), aDst[s]);      \
    GLD_LDS16(bSrc + (kb), bDst[s]);      \
  }

  STG(0, 0);
  STG(1, 64);
  WAIT_VM(2);  // slot0 landed; slot1 stays in flight
  SBAR();

  for (int t = 0; t < 32; ++t) {
    if (t + 2 < 32) STG((t + 2) & 3, (t + 2) * 64);
    const short* buf = lds[t & 3];
    bf16x8 ah = *(const bf16x8*)(buf + aOff);
    bf16x8 al = *(const bf16x8*)(buf + 1024 + aOff);
    bf16x8 bh = *(const bf16x8*)(buf + bOff);
    bf16x8 bl = *(const bf16x8*)(buf + 1024 + bOff);
    acc = __builtin_amdgcn_mfma_f32_16x16x32_bf16(ah, bh, acc, 0, 0, 0);
    acc = __builtin_amdgcn_mfma_f32_16x16x32_bf16(ah, bl, acc, 0, 0, 0);
    acc = __builtin_amdgcn_mfma_f32_16x16x32_bf16(al, bh, acc, 0, 0, 0);
    if (t + 2 < 32) {
      WAIT_VM(2);  // t+1's loads landed; t+2's stay in flight
    } else {
      WAIT_VM(0);
    }
    SBAR();
  }
#undef STG

  const int c = wn * 16 + r15;
  const int rbrow = row0 + wm * 16 + (lane >> 4) * 4;
  const float bias = (c < LOOK) ? b3d[c] : 0.f;
#pragma unroll
  for (int r = 0; r < 4; ++r) {
    const int row = rbrow + r;
    const float kv = acc[r] + bias;
    float zv = 0.f;
    if (c < LOOK) {
      const size_t id = (size_t)row * LOOK + c;
      const float yv = y[id];
      if (combine) {
        float yn = yv + hb1 * K0[id] + hb2 * K1[id] + hb3 * K2[id] +
                   hb4 * K3[id] + hb5 * K4[id] + hb6 * kv;
        y[id] = yn;
        zv = yn;
      } else {
        kout[id] = kv;
        zv = yv + pc * kv;
        if (p1 != 0.f) zv += p1 * K0[id];
        if (p2 != 0.f) zv += p2 * K1[id];
        if (p3 != 0.f) zv += p3 * K2[id];
        if (p4 != 0.f) zv += p4 * K3[id];
        if (p5 != 0.f) zv += p5 * K4[id];
      }
    }
    unsigned short hi = f2bf(zv);
    unsigned short lo = f2bf(zv - bf2f(hi));
    const size_t zo = (size_t)row * 32 + c;
    zh[zo] = (short)hi;
    zl[zo] = (short)lo;
  }
}

// ---------------------------------------------------------------------------
__global__ __launch_bounds__(256) void k_readout(const float* __restrict__ y,
                                                 const float* __restrict__ Wf,
                                                 const float* __restrict__ bf,
                                                 float* __restrict__ out) {
  const int r = blockIdx.x * blockDim.x + threadIdx.x;
  if (r >= BATCH) return;
  float acc = bf[0];
#pragma unroll
  for (int c = 0; c < LOOK; ++c) acc += y[(size_t)r * LOOK + c] * Wf[c];
  out[r] = acc;
}

// ---------------------------------------------------------------------------
extern "C" void kernel_launch(void* const* d_in, const int* in_sizes, int n_in,
                              void* d_out, int out_size, void* d_ws,
                              size_t ws_size, hipStream_t stream) {
  const float* y0 = (const float*)d_in[0];
  const float* W1 = (const float*)d_in[1];
  const float* b1 = (const float*)d_in[2];
  const float* W2 = (const float*)d_in[3];
  const float* b2 = (const float*)d_in[4];
  const float* W3 = (const float*)d_in[5];
  const float* b3 = (const float*)d_in[6];
  const float* Wf = (const float*)d_in[7];
  const float* bf = (const float*)d_in[8];
  float* out = (float*)d_out;

  const size_t NY = (size_t)BATCH * LOOK;
  float* f = (float*)d_ws;
  float* y = f;
  float* kk[5];
  for (int i = 0; i < 5; ++i) kk[i] = f + NY * (1 + i);
  char* p = (char*)(f + NY * 6);
  short* zh = (short*)p; p += (size_t)BATCH * 32 * 2;
  short* zl = (short*)p; p += (size_t)BATCH * 32 * 2;
  short* H1h = (short*)p; p += (size_t)BATCH * HID * 2;
  short* H1l = (short*)p; p += (size_t)BATCH * HID * 2;
  short* H2h = (short*)p; p += (size_t)BATCH * HID * 2;
  short* H2l = (short*)p; p += (size_t)BATCH * HID * 2;
  short* W2Th = (short*)p; p += (size_t)HID * HID * 2;
  short* W2Tl = (short*)p; p += (size_t)HID * HID * 2;
  short* W1Th = (short*)p; p += (size_t)HID * 32 * 2;
  short* W1Tl = (short*)p; p += (size_t)HID * 32 * 2;
  short* W3Th = (short*)p; p += (size_t)32 * HID * 2;
  short* W3Tl = (short*)p;

  hipMemcpyAsync(y, y0, NY * sizeof(float), hipMemcpyDeviceToDevice, stream);
  k_zinit<<<dim3(BATCH * 32 / 256), 256, 0, stream>>>(y0, zh, zl);

  const double hh = 1.0 / 16.0;
  static const double A[6][5] = {
      {0, 0, 0, 0, 0},
      {1.0 / 5, 0, 0, 0, 0},
      {3.0 / 40, 9.0 / 40, 0, 0, 0},
      {44.0 / 45, -56.0 / 15, 32.0 / 9, 0, 0},
      {19372.0 / 6561, -25360.0 / 2187, 64448.0 / 6561, -212.0 / 729, 0},
      {9017.0 / 3168, -355.0 / 33, 46732.0 / 5247, 49.0 / 176,
       -5103.0 / 18656},
  };
  static const double Bb[6] = {35.0 / 384,  0,              500.0 / 1113,
                               125.0 / 192, -2187.0 / 6784, 11.0 / 84};

  const float hb1 = (float)(hh * Bb[0]);
  const float hb2 = (float)(hh * Bb[1]);
  const float hb3 = (float)(hh * Bb[2]);
  const float hb4 = (float)(hh * Bb[3]);
  const float hb5 = (float)(hh * Bb[4]);
  const float hb6 = (float)(hh * Bb[5]);

  for (int d = 0; d < DEPTH; ++d) {
    const float* W1d = W1 + (size_t)d * LOOK * HID;
    const float* b1d = b1 + (size_t)d * HID;
    const float* W2d = W2 + (size_t)d * HID * HID;
    const float* b2d = b2 + (size_t)d * HID;
    const float* W3d = W3 + (size_t)d * HID * LOOK;
    const float* b3d = b3 + (size_t)d * LOOK;

    k_w2split<<<dim3(16, 16), 256, 0, stream>>>(W2d, W2Th, W2Tl);
    k_w1t<<<dim3(128), 256, 0, stream>>>(W1d, W1Th, W1Tl);
    k_w3t<<<dim3(128), 256, 0, stream>>>(W3d, W3Th, W3Tl);

    for (int s = 0; s < NSTEPS; ++s) {
      for (int st = 0; st < 6; ++st) {
        float pv[5] = {0.f, 0.f, 0.f, 0.f, 0.f};
        float pc = 0.f;
        if (st < 5) {
          for (int jj = 0; jj < 5; ++jj)
            if (jj < st) pv[jj] = (float)(hh * A[st + 1][jj]);
          pc = (float)(hh * A[st + 1][st]);
        }
        k_l1<<<dim3(BATCH / 128, HID / 256), 512, 0, stream>>>(
            zh, zl, W1Th, W1Tl, b1d, H1h, H1l);
        k_mid<<<dim3(256), 512, 0, stream>>>(H1h, H1l, W2Th, W2Tl, b2d, H2h,
                                             H2l);
        const int comb = (st == 5) ? 1 : 0;
        float* kout = (st < 5) ? kk[st] : kk[0];
        k_l3<<<dim3(BATCH / 32), 256, 0, stream>>>(
            H2h, H2l, W3Th, W3Tl, b3d, kout, kk[0], kk[1], kk[2], kk[3],
            kk[4], y, zh, zl, comb, pv[0], pv[1], pv[2], pv[3], pv[4], pc,
            hb1, hb2, hb3, hb4, hb5, hb6);
      }
    }
  }

  k_readout<<<dim3(BATCH / 256), 256, 0, stream>>>(y, Wf, bf, out);
}